// Round 11
// baseline (163.487 us; speedup 1.0000x reference)
//
#include <hip/hip_runtime.h>
#include <hip/hip_bf16.h>
#include <stdint.h>
#include <math.h>

// Attention: out = dropout(softmax(8 * Q K^T)) V, B=4 H=16 S=1024 D=64 fp32.
// R20 = R19 + two sync-structure-free VALU/latency levers in tile_step:
//  (1) Softmax||PV interleave: c-blocks 0,1 -> P chunks 0..3 -> PV(ks2=0)
//      -> c-blocks 2,3 -> chunks 4..7 -> PV(ks2=1) -> rs/l_r finalize.
//      PV ks2=0 needs exactly chunks 0..3 (pos algebra verified), so its 4
//      MFMAs overlap c2/c3's exp/push VALU. Same-wave lgkm deps only;
//      bit-identical arithmetic, push order preserved.
//  (2) Push diet: per-c gate (1 ballot on pmx=max4(pc)) before the per-r
//      ballots — identical semantics, common-case ballots 16 -> 4 per tile.
// R19 probe result: prep_kv coalescing did NOT move total (160.7->160.5);
// the ~82us total-vs-attn gap is harness/launch overhead — stop chasing.
// attn side (proven): T1 XCD permutation (FETCH 110->22.5MB), T5 setprio,
// ping-pong dbuf ONE barrier/tile, NT=512 TQM=128, numerics diet (native
// cvts, log2-domain exp2, defer-rescale), S^T = K Q^T, deferred-correction
// dropout (threefry VERIFIED R2). prep_kv: R18 coalesced version (passed).

constexpr int Bn = 4, Hn = 16, Sn = 1024, Dn = 64;
constexpr int NT = 512;   // main kernel: 8 waves/block
constexpr int NTF = 256;  // prep + fallback block size
constexpr int TK = 64;
constexpr int TQM = 128;  // q rows per block (wave w owns rows w*16..w*16+15)
constexpr int CAP = 128;  // per-wave candidate list capacity (overflow path exact)
constexpr int NTILE = Sn / TK;  // 16

typedef short s16x8 __attribute__((ext_vector_type(8)));
typedef short s16x4 __attribute__((ext_vector_type(4)));
typedef float f32x4 __attribute__((ext_vector_type(4)));

__device__ __forceinline__ uint16_t f2bf(float x) {  // RNE float->bf16 (manual)
  uint32_t u = __float_as_uint(x);
  return (uint16_t)((u + 0x7fffu + ((u >> 16) & 1u)) >> 16);
}
__device__ __forceinline__ uint16_t f2bf_fast(float x) {  // RNE via v_cvt (fusable)
  return __builtin_bit_cast(uint16_t, __float2bfloat16(x));
}
__device__ __forceinline__ float bf2f(uint16_t h) {
  return __uint_as_float(((uint32_t)h) << 16);
}
__device__ __forceinline__ float fexp2(float x) {  // v_exp_f32 (2^x)
  return __builtin_amdgcn_exp2f(x);
}

__device__ __forceinline__ void tf_round(uint32_t& x0, uint32_t& x1, const int r) {
  x0 += x1;
  x1 = (x1 << r) | (x1 >> (32 - r));
  x1 ^= x0;
}

// threefry2x32, key(42)=(0,42), counter (0, j), bits = y0^y1  [VERIFIED R2]
__device__ __noinline__ int keep_bit(uint32_t j) {
  uint32_t x0 = 0u, x1 = j;
  const uint32_t k0 = 0u, k1v = 42u;
  const uint32_t k2v = k0 ^ k1v ^ 0x1BD11BDAu;
  x0 += k0; x1 += k1v;
  tf_round(x0, x1, 13); tf_round(x0, x1, 15); tf_round(x0, x1, 26); tf_round(x0, x1, 6);
  x0 += k1v; x1 += k2v + 1u;
  tf_round(x0, x1, 17); tf_round(x0, x1, 29); tf_round(x0, x1, 16); tf_round(x0, x1, 24);
  x0 += k2v; x1 += k0 + 2u;
  tf_round(x0, x1, 13); tf_round(x0, x1, 15); tf_round(x0, x1, 26); tf_round(x0, x1, 6);
  x0 += k0; x1 += k1v + 3u;
  tf_round(x0, x1, 17); tf_round(x0, x1, 29); tf_round(x0, x1, 16); tf_round(x0, x1, 24);
  x0 += k1v; x1 += k2v + 4u;
  tf_round(x0, x1, 13); tf_round(x0, x1, 15); tf_round(x0, x1, 26); tf_round(x0, x1, 6);
  x0 += k2v; x1 += k0 + 5u;
  uint32_t bits = x0 ^ x1;
  float u = __uint_as_float((bits >> 9) | 0x3f800000u) - 1.0f;
  return u < 0.9f;
}

// ---- pre-pass: K split + V transpose, swizzled bf16 tiles (R18: coalesced) ----
__global__ __launch_bounds__(NTF) void prep_kv(const float* __restrict__ K,
                                               const float* __restrict__ V,
                                               uint16_t* __restrict__ Khg,
                                               uint16_t* __restrict__ Klg,
                                               uint16_t* __restrict__ Vtg) {
  __shared__ float Vl[TK][Dn + 1];
  const int t = threadIdx.x;
  const int kt = blockIdx.x;   // 0..15
  const int bh = blockIdx.y;   // 0..63
  const size_t tile = ((size_t)bh * 16 + kt) * 4096;
  const size_t rowbase = (size_t)bh * Sn + (size_t)(kt * TK);

#pragma unroll
  for (int i = 0; i < 2; ++i) {
    const int r = i * 32 + (t >> 3);
    const int c0 = (t & 7) * 8;
    const float* ksrc = K + (rowbase + (size_t)r) * Dn + c0;
    float4 a = *(const float4*)(ksrc);
    float4 b = *(const float4*)(ksrc + 4);
    float xs[8] = {a.x, a.y, a.z, a.w, b.x, b.y, b.z, b.w};
    s16x8 hv, lv;
#pragma unroll
    for (int j = 0; j < 8; ++j) {
      uint16_t hb = f2bf_fast(xs[j]);
      hv[j] = (short)hb;
      lv[j] = (short)f2bf_fast(xs[j] - bf2f(hb));
    }
    const int sc = (t & 7) ^ (r & 7);   // chunk = c0/8 = t&7
    *(s16x8*)&Khg[tile + (size_t)r * 64 + sc * 8] = hv;
    *(s16x8*)&Klg[tile + (size_t)r * 64 + sc * 8] = lv;
    const float* vsrc = V + (rowbase + (size_t)r) * Dn + c0;
    float4 va = *(const float4*)(vsrc);
    float4 vb = *(const float4*)(vsrc + 4);
    *(float4*)&Vl[r][c0] = va;
    *(float4*)&Vl[r][c0 + 4] = vb;
  }
  __syncthreads();
  {
    const int r = t >> 2, qd = t & 3;
#pragma unroll
    for (int half = 0; half < 2; ++half) {
      s16x8 ov;
#pragma unroll
      for (int j = 0; j < 8; ++j)
        ov[j] = (short)f2bf_fast(Vl[qd * 16 + half * 8 + j][r]);
      const int sc = (qd * 2 + half) ^ (r & 7);
      *(s16x8*)&Vtg[tile + (size_t)r * 64 + sc * 8] = ov;
    }
  }
}

// -------- main flash kernel: S^T orientation, TQ=128, 8 waves, dbuf ping-pong --------
__global__ __launch_bounds__(NT, 4) void attn_mfma7(
    const float* __restrict__ Q, const uint16_t* __restrict__ Khg,
    const uint16_t* __restrict__ Klg, const uint16_t* __restrict__ Vtg,
    const float* __restrict__ V, const int* __restrict__ scale_ptr,
    float* __restrict__ out) {
  __shared__ uint16_t KhS[2][TK * Dn];   // 2 x 8 KB ping-pong (DMA dest, swizzled)
  __shared__ uint16_t KlS[2][TK * Dn];
  __shared__ uint16_t VtS[2][TK * Dn];
  __shared__ uint16_t PS[8 * 16 * 64];   // per-wave P[q][key], XOR-chunk swizzled
  __shared__ uint32_t Lm[8][CAP];        // per-wave candidate list: (rw<<10)|key
  __shared__ float Lsv[8][CAP];          // candidate raw logit s (log2 domain)
  __shared__ float mfin[8][16];          // per-wave final row max (log2 domain)

  const int t = threadIdx.x;
  const int w = t >> 6;                  // 0..7
  const int lane = t & 63;
  const int l16 = lane & 15;
  const int quad = lane >> 4;
  const int xl = l16 & 7;                // XOR swizzle key

  // ---- T1: XCD-aware work permutation. Grid (8,16,4); XCD = linear%8 = x.
  // bh = x*8+(y&7), qb = (y>>3)*4+z [bijective]: all 8 q-blocks of one bh on
  // one XCD -> per-XCD ws footprint 3MB fits its 4MB L2 (FETCH 110->22.5MB).
  const int bh = blockIdx.x * 8 + (blockIdx.y & 7);
  const int qb = ((blockIdx.y >> 3) << 2) | blockIdx.z;
  const int qbase = qb * TQM;
  // log2(e) folded into the Q pre-scale: all logits live in the log2 domain.
  const float qscale = (float)(*scale_ptr) * 1.44269504089f;
  const float pthr = 1.670170079e-5f;    // exp(-11), in the p domain (unchanged)

  // per-wave DMA segment: wave w covers elements [w*512, w*512+512) of each tile
  const int eoff = w * 512 + lane * 8;
  const size_t tbase = (size_t)bh * 16 * 4096;
  const int psw = w * 1024;              // per-wave PS base (elements)

  auto issue3 = [&](int ti, int pb) {    // stage Kh,Kl,Vt of tile ti into buf pb
    const size_t tile = tbase + (size_t)ti * 4096;
    __builtin_amdgcn_global_load_lds(
        (const __attribute__((address_space(1))) uint32_t*)(Khg + tile + eoff),
        (__attribute__((address_space(3))) uint32_t*)(&KhS[pb][eoff]), 16, 0, 0);
    __builtin_amdgcn_global_load_lds(
        (const __attribute__((address_space(1))) uint32_t*)(Klg + tile + eoff),
        (__attribute__((address_space(3))) uint32_t*)(&KlS[pb][eoff]), 16, 0, 0);
    __builtin_amdgcn_global_load_lds(
        (const __attribute__((address_space(1))) uint32_t*)(Vtg + tile + eoff),
        (__attribute__((address_space(3))) uint32_t*)(&VtS[pb][eoff]), 16, 0, 0);
  };

  // prologue: tile 0 -> buf0 in flight; Q load/split overlaps it
  issue3(0, 0);

  // ---- Q B-frags (pre-scaled, log2 domain): wave w owns q rows qbase+w*16+l16 ----
  s16x8 qh[2], ql[2];
  {
    const int qrow = qbase + w * 16 + l16;
    const float* src = Q + ((size_t)bh * Sn + (size_t)qrow) * Dn;
#pragma unroll
    for (int ks = 0; ks < 2; ++ks) {
      float4 x0 = *(const float4*)(src + ks * 32 + quad * 8);
      float4 x1 = *(const float4*)(src + ks * 32 + quad * 8 + 4);
      float xv[8] = {x0.x, x0.y, x0.z, x0.w, x1.x, x1.y, x1.z, x1.w};
#pragma unroll
      for (int j = 0; j < 8; ++j) {
        const float xs = xv[j] * qscale;
        uint16_t hb = f2bf_fast(xs);
        qh[ks][j] = (short)hb;
        ql[ks][j] = (short)f2bf_fast(xs - bf2f(hb));
      }
    }
  }

  // per-lane softmax state: ONE q per lane (log2 domain)
  float m_r = -INFINITY, l_r = 0.0f;
  // O^T accumulator: o_acc[c][r] = O[q = l16][dv = c*16+quad*4+r]
  f32x4 o_acc[4];
#pragma unroll
  for (int c = 0; c < 4; ++c) o_acc[c] = (f32x4){0.f, 0.f, 0.f, 0.f};

  const uint32_t hbase = (uint32_t)bh * (uint32_t)Sn;
  int lbase = 0;  // per-wave list fill (wave-uniform)

  // one tile's QK -> softmax||PV interleave, reading buffers [pb]
  auto tile_step = [&](int kbase, int pb) {
    // ---- S^T = K Q^T: A = K tile (LDS), B = Q (regs), split-bf16 3-MFMA ----
    f32x4 sacc[4];
#pragma unroll
    for (int c = 0; c < 4; ++c) sacc[c] = (f32x4){0.f, 0.f, 0.f, 0.f};
    __builtin_amdgcn_s_setprio(1);     // T5: favor MFMA cluster
#pragma unroll
    for (int ks = 0; ks < 2; ++ks) {
#pragma unroll
      for (int c = 0; c < 4; ++c) {
        const int boff = (c * 16 + l16) * 64 + (((ks * 4 + quad) ^ xl) * 8);
        const s16x8 khv = *(const s16x8*)&KhS[pb][boff];
        const s16x8 klv = *(const s16x8*)&KlS[pb][boff];
        sacc[c] = __builtin_amdgcn_mfma_f32_16x16x32_bf16(khv, qh[ks], sacc[c], 0, 0, 0);
        sacc[c] = __builtin_amdgcn_mfma_f32_16x16x32_bf16(khv, ql[ks], sacc[c], 0, 0, 0);
        sacc[c] = __builtin_amdgcn_mfma_f32_16x16x32_bf16(klv, qh[ks], sacc[c], 0, 0, 0);
      }
    }
    __builtin_amdgcn_s_setprio(0);

    // ---- softmax prologue: row max + defer-rescale (unchanged) ----
    float mx = sacc[0][0];
#pragma unroll
    for (int c = 0; c < 4; ++c)
#pragma unroll
      for (int r = 0; r < 4; ++r) mx = fmaxf(mx, sacc[c][r]);
    mx = fmaxf(mx, __shfl_xor(mx, 16));
    mx = fmaxf(mx, __shfl_xor(mx, 32));  // row max over all 64 keys of tile

    // defer-rescale: if no lane's max grew, alpha==1 exactly -> skip the pass
    if (__ballot(mx > m_r) != 0ull) {
      const float mn = fmaxf(m_r, mx);
      const float al = fexp2(m_r - mn);  // 0 on first tile
      m_r = mn;
#pragma unroll
      for (int c = 0; c < 4; ++c)
#pragma unroll
        for (int r = 0; r < 4; ++r) o_acc[c][r] *= al;
      l_r *= al;
    }

    // -15.88 < -11*log2(e): gate true whenever any pc can exceed pthr
    const bool anyhot = __ballot(mx - m_r > -15.88f) != 0ull;
    float rs = 0.0f;

    // per-c softmax body: exp, gated push (per-c pmx ballot), P chunk store
    auto do_c = [&](int c) {
      float pc[4];
#pragma unroll
      for (int r = 0; r < 4; ++r) {
        pc[r] = fexp2(sacc[c][r] - m_r);
        rs += pc[r];  // UNMASKED row sum (softmax normalizes before dropout)
      }
      if (anyhot) {
        const float pmx = fmaxf(fmaxf(pc[0], pc[1]), fmaxf(pc[2], pc[3]));
        if (__ballot(pmx > pthr) != 0ull) {  // per-c gate: 1 ballot common case
#pragma unroll
          for (int r = 0; r < 4; ++r) {
            const uint64_t mc = __ballot(pc[r] > pthr);
            if (mc != 0ull) {
              if (lbase + 64 <= CAP) {
                const int slot = lbase + (int)__popcll(mc & ((1ull << lane) - 1ull));
                if (pc[r] > pthr) {
                  Lm[w][slot] = ((uint32_t)l16 << 10) |
                                (uint32_t)(kbase + c * 16 + quad * 4 + r);
                  Lsv[w][slot] = sacc[c][r];  // raw logit (log2 domain)
                }
                lbase += (int)__popcll(mc);
              } else if (pc[r] > pthr) {  // overflow: inline exact dropout
                const uint32_t j =
                    (hbase + (uint32_t)(qbase + w * 16 + l16)) * (uint32_t)Sn +
                    (uint32_t)(kbase + c * 16 + quad * 4 + r);
                if (!keep_bit(j)) pc[r] = 0.0f;  // rs already added (unmasked)
              }
            }
          }
        }
      }
      // P store: 4 consecutive keys -> b64, XOR-chunk swizzled (native cvt)
      s16x4 pk;
#pragma unroll
      for (int r = 0; r < 4; ++r) pk[r] = (short)f2bf_fast(pc[r]);
      const int pos = (c * 2 + (quad >> 1)) ^ xl;
      *(s16x4*)&PS[psw + l16 * 64 + pos * 8 + (quad & 1) * 4] = pk;
    };
    // one PV half: key-chunks ks2*4..ks2*4+3 (written by c-blocks 2*ks2,2*ks2+1)
    auto pv_half = [&](int ks2) {
      __builtin_amdgcn_s_setprio(1);   // T5
      const s16x8 pfr = *(const s16x8*)&PS[psw + l16 * 64 + (((ks2 * 4 + quad) ^ xl) * 8)];
#pragma unroll
      for (int c = 0; c < 4; ++c) {
        const int voff = (c * 16 + l16) * 64 + (((ks2 * 4 + quad) ^ xl) * 8);
        const s16x8 vb = *(const s16x8*)&VtS[pb][voff];
        o_acc[c] = __builtin_amdgcn_mfma_f32_16x16x32_bf16(vb, pfr, o_acc[c], 0, 0, 0);
      }
      __builtin_amdgcn_s_setprio(0);
    };

    // ---- interleave: c01 -> PV(ks2=0) overlaps c23 -> PV(ks2=1) ----
    do_c(0); do_c(1);
    pv_half(0);          // MFMA on chunks 0..3 while VALU runs c2,c3
    do_c(2); do_c(3);
    pv_half(1);

    // rs finalize after PV issue (independent of PV)
    rs += __shfl_xor(rs, 16);
    rs += __shfl_xor(rs, 32);
    l_r += rs;
  };

  // ---- ping-pong main loop: ONE barrier per tile, prefetch into other buffer ----
  for (int kt = 0; kt < NTILE; kt += 2) {
    __syncthreads();               // own vmcnt(0) drained -> buf0(kt) visible to all;
                                   // all waves done reading buf1 (tile kt-1)
    issue3(kt + 1, 1);             // kt+1 <= 15 always (NTILE even)
    tile_step(kt * TK, 0);
    __syncthreads();               // buf1(kt+1) visible; all done reading buf0(kt)
    if (kt + 2 < NTILE) issue3(kt + 2, 0);
    tile_step((kt + 1) * TK, 1);
  }

  // ---- drain: dense threefry over candidate list, subtract dropped p*V ----
  if (quad == 0) mfin[w][l16] = m_r;
  for (int e0 = 0; e0 < lbase; e0 += 64) {
    const int e = e0 + lane;
    const bool valid = e < lbase;
    const uint32_t meta = valid ? Lm[w][e] : 0u;
    const float sv = valid ? Lsv[w][e] : 0.0f;
    const uint32_t rwv = meta >> 10, keyv = meta & 1023u;
    const uint32_t grow = (uint32_t)(qbase + w * 16) + rwv;
    const uint32_t j = (hbase + grow) * (uint32_t)Sn + keyv;
    const int kb = keep_bit(j);  // dense: all 64 lanes productive
    uint64_t dm = __ballot(valid && !kb);
    while (dm != 0ull) {
      const int src = (int)__builtin_ctzll(dm);
      dm &= dm - 1ull;
      const uint32_t meta_s = (uint32_t)__builtin_amdgcn_readlane((int)meta, src);
      const float sv_s =
          __uint_as_float((uint32_t)__builtin_amdgcn_readlane((int)__float_as_uint(sv), src));
      const int rw = (int)(meta_s >> 10);
      const int key = (int)(meta_s & 1023u);
      const float p = fexp2(sv_s - mfin[w][rw]);   // log2 domain
      const float pb2 = bf2f(f2bf_fast(p));        // matches stored bf16(P) bits
      if (rw == l16) {  // the 4 quads owning column q participate
        const float* vp = V + ((size_t)bh * Sn + (size_t)key) * Dn;
#pragma unroll
        for (int c = 0; c < 4; ++c) {
          float4 vv = *(const float4*)(vp + c * 16 + quad * 4);
          o_acc[c][0] = fmaf(-pb2, bf2f(f2bf(vv.x)), o_acc[c][0]);
          o_acc[c][1] = fmaf(-pb2, bf2f(f2bf(vv.y)), o_acc[c][1]);
          o_acc[c][2] = fmaf(-pb2, bf2f(f2bf(vv.z)), o_acc[c][2]);
          o_acc[c][3] = fmaf(-pb2, bf2f(f2bf(vv.w)), o_acc[c][3]);
        }
      }
    }
  }

  // ---- epilogue: out[q][dv] = O^T / (l * 0.9); per-lane scalar scale ----
  {
    const float inv = 1.0f / (l_r * 0.9f);
    const size_t obase = ((size_t)bh * Sn + (size_t)(qbase + w * 16 + l16)) * Dn;
#pragma unroll
    for (int c = 0; c < 4; ++c) {
      float4 ov;
      ov.x = o_acc[c][0] * inv;
      ov.y = o_acc[c][1] * inv;
      ov.z = o_acc[c][2] * inv;
      ov.w = o_acc[c][3] * inv;
      *(float4*)(out + obase + c * 16 + quad * 4) = ov;
    }
  }
}

// ---------------- fallback (R3 kernel, verbatim): used only if ws too small ----------------
constexpr int KST = 72;
__global__ __launch_bounds__(NTF) void attn_fallback(
    const float* __restrict__ Q, const float* __restrict__ K,
    const float* __restrict__ V, const int* __restrict__ scale_ptr,
    float* __restrict__ out) {
  __shared__ uint16_t KhS[64 * KST];
  __shared__ uint16_t KlS[64 * KST];
  __shared__ uint16_t VtS[Dn * KST];
  __shared__ uint16_t PSf[4 * 16 * KST];

  const int t = threadIdx.x;
  const int w = t >> 6;
  const int lane = t & 63;
  const int l16 = lane & 15;
  const int quad = lane >> 4;
  const int b = blockIdx.z, h = blockIdx.y;
  const int qbase = blockIdx.x * 64;
  const size_t bh = (size_t)b * Hn + h;
  const float scale = (float)(*scale_ptr);
  const float* Kp = K + bh * Sn * Dn;
  const float* Vp = V + bh * Sn * Dn;

  const int qrow = qbase + w * 16 + l16;
  const float* Qp = Q + (bh * Sn + (size_t)qrow) * Dn;
  s16x8 qh[2], ql[2];
#pragma unroll
  for (int ks = 0; ks < 2; ++ks) {
    const float* src = Qp + ks * 32 + quad * 8;
    float4 x0 = *(const float4*)(src);
    float4 x1 = *(const float4*)(src + 4);
    float xv[8] = {x0.x, x0.y, x0.z, x0.w, x1.x, x1.y, x1.z, x1.w};
#pragma unroll
    for (int j = 0; j < 8; ++j) {
      uint16_t hb = f2bf(xv[j]);
      qh[ks][j] = (short)hb;
      ql[ks][j] = (short)f2bf(xv[j] - bf2f(hb));
    }
  }
  const int kr = t >> 2;
  const int qd = t & 3;
  float m_r[4], l_r[4];
#pragma unroll
  for (int r = 0; r < 4; ++r) { m_r[r] = -INFINITY; l_r[r] = 0.0f; }
  f32x4 o_acc[4];
#pragma unroll
  for (int c = 0; c < 4; ++c) o_acc[c] = (f32x4){0.f, 0.f, 0.f, 0.f};
  const uint32_t rowlin = ((uint32_t)(b * Hn + h)) * (uint32_t)Sn +
                          (uint32_t)(qbase + w * 16 + quad * 4);
  for (int kt = 0; kt < Sn / 64; ++kt) {
    const int kbase = kt * 64;
    __syncthreads();
    {
      const float* ksrc = Kp + (size_t)(kbase + kr) * Dn + qd * 16;
#pragma unroll
      for (int half = 0; half < 2; ++half) {
        float4 a = *(const float4*)(ksrc + half * 8);
        float4 b2 = *(const float4*)(ksrc + half * 8 + 4);
        float xs[8] = {a.x, a.y, a.z, a.w, b2.x, b2.y, b2.z, b2.w};
        s16x8 hv, lv;
#pragma unroll
        for (int j = 0; j < 8; ++j) {
          uint16_t hb = f2bf(xs[j]);
          hv[j] = (short)hb;
          lv[j] = (short)f2bf(xs[j] - bf2f(hb));
        }
        *(s16x8*)&KhS[kr * KST + qd * 16 + half * 8] = hv;
        *(s16x8*)&KlS[kr * KST + qd * 16 + half * 8] = lv;
      }
      const float* vsrc = Vp + (size_t)(kbase + kr) * Dn + qd * 16;
#pragma unroll
      for (int half = 0; half < 2; ++half) {
        float4 a = *(const float4*)(vsrc + half * 8);
        float4 b2 = *(const float4*)(vsrc + half * 8 + 4);
        float xs[8] = {a.x, a.y, a.z, a.w, b2.x, b2.y, b2.z, b2.w};
#pragma unroll
        for (int j = 0; j < 8; ++j)
          VtS[(qd * 16 + half * 8 + j) * KST + kr] = f2bf(xs[j]);
      }
    }
    __syncthreads();
    f32x4 sacc[4];
#pragma unroll
    for (int c = 0; c < 4; ++c) sacc[c] = (f32x4){0.f, 0.f, 0.f, 0.f};
#pragma unroll
    for (int ks = 0; ks < 2; ++ks) {
#pragma unroll
      for (int c = 0; c < 4; ++c) {
        const s16x8 bh_ = *(const s16x8*)&KhS[(c * 16 + l16) * KST + ks * 32 + quad * 8];
        const s16x8 bl_ = *(const s16x8*)&KlS[(c * 16 + l16) * KST + ks * 32 + quad * 8];
        sacc[c] = __builtin_amdgcn_mfma_f32_16x16x32_bf16(qh[ks], bh_, sacc[c], 0, 0, 0);
        sacc[c] = __builtin_amdgcn_mfma_f32_16x16x32_bf16(ql[ks], bh_, sacc[c], 0, 0, 0);
        sacc[c] = __builtin_amdgcn_mfma_f32_16x16x32_bf16(qh[ks], bl_, sacc[c], 0, 0, 0);
      }
    }
    float mx[4];
#pragma unroll
    for (int r = 0; r < 4; ++r) {
      mx[r] = sacc[0][r] * scale;
#pragma unroll
      for (int c = 1; c < 4; ++c) mx[r] = fmaxf(mx[r], sacc[c][r] * scale);
#pragma unroll
      for (int d = 1; d < 16; d <<= 1) mx[r] = fmaxf(mx[r], __shfl_xor(mx[r], d));
    }
    float al[4];
#pragma unroll
    for (int r = 0; r < 4; ++r) {
      const float mn = fmaxf(m_r[r], mx[r]);
      al[r] = __expf(m_r[r] - mn);
      m_r[r] = mn;
    }
#pragma unroll
    for (int c = 0; c < 4; ++c)
#pragma unroll
      for (int r = 0; r < 4; ++r) o_acc[c][r] *= al[r];
    float rs[4] = {0.f, 0.f, 0.f, 0.f};
#pragma unroll
    for (int c = 0; c < 4; ++c) {
#pragma unroll
      for (int r = 0; r < 4; ++r) {
        const float d = sacc[c][r] * scale - m_r[r];
        float pv = __expf(d);
        rs[r] += pv;
        if (d > -25.0f) {
          const uint32_t j = (rowlin + (uint32_t)r) * (uint32_t)Sn +
                             (uint32_t)(kbase + c * 16 + l16);
          if (!keep_bit(j)) pv = 0.0f;
        }
        PSf[(w * 16 + quad * 4 + r) * KST + c * 16 + l16] = f2bf(pv);
      }
    }
#pragma unroll
    for (int r = 0; r < 4; ++r) {
#pragma unroll
      for (int d = 1; d < 16; d <<= 1) rs[r] += __shfl_xor(rs[r], d);
      l_r[r] = l_r[r] * al[r] + rs[r];
    }
#pragma unroll
    for (int ks2 = 0; ks2 < 2; ++ks2) {
      const s16x8 pa = *(const s16x8*)&PSf[(w * 16 + l16) * KST + ks2 * 32 + quad * 8];
#pragma unroll
      for (int c = 0; c < 4; ++c) {
        const s16x8 vb = *(const s16x8*)&VtS[(c * 16 + l16) * KST + ks2 * 32 + quad * 8];
        o_acc[c] = __builtin_amdgcn_mfma_f32_16x16x32_bf16(pa, vb, o_acc[c], 0, 0, 0);
      }
    }
  }
  float inv[4];
#pragma unroll
  for (int r = 0; r < 4; ++r) inv[r] = 1.0f / (l_r[r] * 0.9f);
#pragma unroll
  for (int c = 0; c < 4; ++c)
#pragma unroll
    for (int r = 0; r < 4; ++r)
      out[(bh * Sn + (size_t)(qbase + w * 16 + quad * 4 + r)) * Dn + c * 16 + l16] =
          o_acc[c][r] * inv[r];
}

extern "C" void kernel_launch(void* const* d_in, const int* in_sizes, int n_in,
                              void* d_out, int out_size, void* d_ws, size_t ws_size,
                              hipStream_t stream) {
  const float* Q = (const float*)d_in[0];
  const float* K = (const float*)d_in[1];
  const float* V = (const float*)d_in[2];
  const int* sf = (const int*)d_in[3];
  float* out = (float*)d_out;

  constexpr size_t ARR = (size_t)Bn * Hn * Sn * Dn;  // 4,194,304 elems (8 MB bf16)
  const size_t need = 3 * ARR * sizeof(uint16_t);    // 24 MB

  if (ws_size >= need) {
    uint16_t* Khg = (uint16_t*)d_ws;
    uint16_t* Klg = Khg + ARR;
    uint16_t* Vtg = Klg + ARR;
    prep_kv<<<dim3(16, 64), NTF, 0, stream>>>(K, V, Khg, Klg, Vtg);
    attn_mfma7<<<dim3(Sn / TQM, Hn, Bn), NT, 0, stream>>>(Q, Khg, Klg, Vtg, V, sf, out);
  } else {
    attn_fallback<<<dim3(Sn / 64, Hn, Bn), NTF, 0, stream>>>(Q, K, V, sf, out);
  }
}

// Round 12
// 161.003 us; speedup vs baseline: 1.0154x; 1.0154x over previous
//
#include <hip/hip_runtime.h>
#include <hip/hip_bf16.h>
#include <stdint.h>
#include <math.h>

// Attention: out = dropout(softmax(8 * Q K^T)) V, B=4 H=16 S=1024 D=64 fp32.
// R21 = attn REVERTED to R19 (proven 78.5us; R20's softmax||PV interleave
// REGRESSED to 83.0us — split PV doubled the exposed P-store->P-read LDS
// RAW turnarounds, and the pmx push-gate added ballots since anyhot is
// almost always true) + prep_kv block-merge 4x (grid (4,64), 4 tiles/block):
// R19 showed prep is not BW-bound (coalescing moved nothing); this probes
// the launch/latency-bound hypothesis for the fixed ~82us total-attn gap.
// attn side (proven): T1 XCD permutation (FETCH 110->22.5MB), T5 setprio,
// ping-pong dbuf ONE barrier/tile, NT=512 TQM=128, numerics diet (native
// cvts, log2-domain exp2, defer-rescale), S^T = K Q^T, deferred-correction
// dropout (threefry VERIFIED R2). prep: R18 coalesced layout, same bytes.

constexpr int Bn = 4, Hn = 16, Sn = 1024, Dn = 64;
constexpr int NT = 512;   // main kernel: 8 waves/block
constexpr int NTF = 256;  // prep + fallback block size
constexpr int TK = 64;
constexpr int TQM = 128;  // q rows per block (wave w owns rows w*16..w*16+15)
constexpr int CAP = 128;  // per-wave candidate list capacity (overflow path exact)
constexpr int NTILE = Sn / TK;  // 16

typedef short s16x8 __attribute__((ext_vector_type(8)));
typedef short s16x4 __attribute__((ext_vector_type(4)));
typedef float f32x4 __attribute__((ext_vector_type(4)));

__device__ __forceinline__ uint16_t f2bf(float x) {  // RNE float->bf16 (manual)
  uint32_t u = __float_as_uint(x);
  return (uint16_t)((u + 0x7fffu + ((u >> 16) & 1u)) >> 16);
}
__device__ __forceinline__ uint16_t f2bf_fast(float x) {  // RNE via v_cvt (fusable)
  return __builtin_bit_cast(uint16_t, __float2bfloat16(x));
}
__device__ __forceinline__ float bf2f(uint16_t h) {
  return __uint_as_float(((uint32_t)h) << 16);
}
__device__ __forceinline__ float fexp2(float x) {  // v_exp_f32 (2^x)
  return __builtin_amdgcn_exp2f(x);
}

__device__ __forceinline__ void tf_round(uint32_t& x0, uint32_t& x1, const int r) {
  x0 += x1;
  x1 = (x1 << r) | (x1 >> (32 - r));
  x1 ^= x0;
}

// threefry2x32, key(42)=(0,42), counter (0, j), bits = y0^y1  [VERIFIED R2]
__device__ __noinline__ int keep_bit(uint32_t j) {
  uint32_t x0 = 0u, x1 = j;
  const uint32_t k0 = 0u, k1v = 42u;
  const uint32_t k2v = k0 ^ k1v ^ 0x1BD11BDAu;
  x0 += k0; x1 += k1v;
  tf_round(x0, x1, 13); tf_round(x0, x1, 15); tf_round(x0, x1, 26); tf_round(x0, x1, 6);
  x0 += k1v; x1 += k2v + 1u;
  tf_round(x0, x1, 17); tf_round(x0, x1, 29); tf_round(x0, x1, 16); tf_round(x0, x1, 24);
  x0 += k2v; x1 += k0 + 2u;
  tf_round(x0, x1, 13); tf_round(x0, x1, 15); tf_round(x0, x1, 26); tf_round(x0, x1, 6);
  x0 += k0; x1 += k1v + 3u;
  tf_round(x0, x1, 17); tf_round(x0, x1, 29); tf_round(x0, x1, 16); tf_round(x0, x1, 24);
  x0 += k1v; x1 += k2v + 4u;
  tf_round(x0, x1, 13); tf_round(x0, x1, 15); tf_round(x0, x1, 26); tf_round(x0, x1, 6);
  x0 += k2v; x1 += k0 + 5u;
  uint32_t bits = x0 ^ x1;
  float u = __uint_as_float((bits >> 9) | 0x3f800000u) - 1.0f;
  return u < 0.9f;
}

// ---- pre-pass: K split + V transpose, swizzled bf16 tiles.
// R21: block-merge 4x — grid (4,64), each block does 4 kt tiles (launch-
// overhead probe). Per-tile thread mapping and output bytes IDENTICAL. ----
__global__ __launch_bounds__(NTF) void prep_kv(const float* __restrict__ K,
                                               const float* __restrict__ V,
                                               uint16_t* __restrict__ Khg,
                                               uint16_t* __restrict__ Klg,
                                               uint16_t* __restrict__ Vtg) {
  __shared__ float Vl[TK][Dn + 1];
  const int t = threadIdx.x;
  const int bh = blockIdx.y;   // 0..63
  for (int kt2 = 0; kt2 < 4; ++kt2) {
    const int kt = blockIdx.x * 4 + kt2;   // 0..15
    const size_t tile = ((size_t)bh * 16 + kt) * 4096;
    const size_t rowbase = (size_t)bh * Sn + (size_t)(kt * TK);

    if (kt2 != 0) __syncthreads();  // Vl reuse: prev transpose reads done
#pragma unroll
    for (int i = 0; i < 2; ++i) {
      const int r = i * 32 + (t >> 3);
      const int c0 = (t & 7) * 8;
      const float* ksrc = K + (rowbase + (size_t)r) * Dn + c0;
      float4 a = *(const float4*)(ksrc);
      float4 b = *(const float4*)(ksrc + 4);
      float xs[8] = {a.x, a.y, a.z, a.w, b.x, b.y, b.z, b.w};
      s16x8 hv, lv;
#pragma unroll
      for (int j = 0; j < 8; ++j) {
        uint16_t hb = f2bf_fast(xs[j]);
        hv[j] = (short)hb;
        lv[j] = (short)f2bf_fast(xs[j] - bf2f(hb));
      }
      const int sc = (t & 7) ^ (r & 7);   // chunk = c0/8 = t&7
      *(s16x8*)&Khg[tile + (size_t)r * 64 + sc * 8] = hv;
      *(s16x8*)&Klg[tile + (size_t)r * 64 + sc * 8] = lv;
      const float* vsrc = V + (rowbase + (size_t)r) * Dn + c0;
      float4 va = *(const float4*)(vsrc);
      float4 vb = *(const float4*)(vsrc + 4);
      *(float4*)&Vl[r][c0] = va;
      *(float4*)&Vl[r][c0 + 4] = vb;
    }
    __syncthreads();
    {
      const int r = t >> 2, qd = t & 3;
#pragma unroll
      for (int half = 0; half < 2; ++half) {
        s16x8 ov;
#pragma unroll
        for (int j = 0; j < 8; ++j)
          ov[j] = (short)f2bf_fast(Vl[qd * 16 + half * 8 + j][r]);
        const int sc = (qd * 2 + half) ^ (r & 7);
        *(s16x8*)&Vtg[tile + (size_t)r * 64 + sc * 8] = ov;
      }
    }
  }
}

// -------- main flash kernel: S^T orientation, TQ=128, 8 waves, dbuf ping-pong --------
__global__ __launch_bounds__(NT, 4) void attn_mfma7(
    const float* __restrict__ Q, const uint16_t* __restrict__ Khg,
    const uint16_t* __restrict__ Klg, const uint16_t* __restrict__ Vtg,
    const float* __restrict__ V, const int* __restrict__ scale_ptr,
    float* __restrict__ out) {
  __shared__ uint16_t KhS[2][TK * Dn];   // 2 x 8 KB ping-pong (DMA dest, swizzled)
  __shared__ uint16_t KlS[2][TK * Dn];
  __shared__ uint16_t VtS[2][TK * Dn];
  __shared__ uint16_t PS[8 * 16 * 64];   // per-wave P[q][key], XOR-chunk swizzled
  __shared__ uint32_t Lm[8][CAP];        // per-wave candidate list: (rw<<10)|key
  __shared__ float Lsv[8][CAP];          // candidate raw logit s (log2 domain)
  __shared__ float mfin[8][16];          // per-wave final row max (log2 domain)

  const int t = threadIdx.x;
  const int w = t >> 6;                  // 0..7
  const int lane = t & 63;
  const int l16 = lane & 15;
  const int quad = lane >> 4;
  const int xl = l16 & 7;                // XOR swizzle key

  // ---- T1: XCD-aware work permutation. Grid (8,16,4); XCD = linear%8 = x.
  // bh = x*8+(y&7), qb = (y>>3)*4+z [bijective]: all 8 q-blocks of one bh on
  // one XCD -> per-XCD ws footprint 3MB fits its 4MB L2 (FETCH 110->22.5MB).
  const int bh = blockIdx.x * 8 + (blockIdx.y & 7);
  const int qb = ((blockIdx.y >> 3) << 2) | blockIdx.z;
  const int qbase = qb * TQM;
  // log2(e) folded into the Q pre-scale: all logits live in the log2 domain.
  const float qscale = (float)(*scale_ptr) * 1.44269504089f;
  const float pthr = 1.670170079e-5f;    // exp(-11), in the p domain (unchanged)

  // per-wave DMA segment: wave w covers elements [w*512, w*512+512) of each tile
  const int eoff = w * 512 + lane * 8;
  const size_t tbase = (size_t)bh * 16 * 4096;
  const int psw = w * 1024;              // per-wave PS base (elements)

  auto issue3 = [&](int ti, int pb) {    // stage Kh,Kl,Vt of tile ti into buf pb
    const size_t tile = tbase + (size_t)ti * 4096;
    __builtin_amdgcn_global_load_lds(
        (const __attribute__((address_space(1))) uint32_t*)(Khg + tile + eoff),
        (__attribute__((address_space(3))) uint32_t*)(&KhS[pb][eoff]), 16, 0, 0);
    __builtin_amdgcn_global_load_lds(
        (const __attribute__((address_space(1))) uint32_t*)(Klg + tile + eoff),
        (__attribute__((address_space(3))) uint32_t*)(&KlS[pb][eoff]), 16, 0, 0);
    __builtin_amdgcn_global_load_lds(
        (const __attribute__((address_space(1))) uint32_t*)(Vtg + tile + eoff),
        (__attribute__((address_space(3))) uint32_t*)(&VtS[pb][eoff]), 16, 0, 0);
  };

  // prologue: tile 0 -> buf0 in flight; Q load/split overlaps it
  issue3(0, 0);

  // ---- Q B-frags (pre-scaled, log2 domain): wave w owns q rows qbase+w*16+l16 ----
  s16x8 qh[2], ql[2];
  {
    const int qrow = qbase + w * 16 + l16;
    const float* src = Q + ((size_t)bh * Sn + (size_t)qrow) * Dn;
#pragma unroll
    for (int ks = 0; ks < 2; ++ks) {
      float4 x0 = *(const float4*)(src + ks * 32 + quad * 8);
      float4 x1 = *(const float4*)(src + ks * 32 + quad * 8 + 4);
      float xv[8] = {x0.x, x0.y, x0.z, x0.w, x1.x, x1.y, x1.z, x1.w};
#pragma unroll
      for (int j = 0; j < 8; ++j) {
        const float xs = xv[j] * qscale;
        uint16_t hb = f2bf_fast(xs);
        qh[ks][j] = (short)hb;
        ql[ks][j] = (short)f2bf_fast(xs - bf2f(hb));
      }
    }
  }

  // per-lane softmax state: ONE q per lane (log2 domain)
  float m_r = -INFINITY, l_r = 0.0f;
  // O^T accumulator: o_acc[c][r] = O[q = l16][dv = c*16+quad*4+r]
  f32x4 o_acc[4];
#pragma unroll
  for (int c = 0; c < 4; ++c) o_acc[c] = (f32x4){0.f, 0.f, 0.f, 0.f};

  const uint32_t hbase = (uint32_t)bh * (uint32_t)Sn;
  int lbase = 0;  // per-wave list fill (wave-uniform)

  // one tile's QK -> softmax -> PV, reading buffers [pb]  (R19-proven body)
  auto tile_step = [&](int kbase, int pb) {
    // ---- S^T = K Q^T: A = K tile (LDS), B = Q (regs), split-bf16 3-MFMA ----
    f32x4 sacc[4];
#pragma unroll
    for (int c = 0; c < 4; ++c) sacc[c] = (f32x4){0.f, 0.f, 0.f, 0.f};
    __builtin_amdgcn_s_setprio(1);     // T5: favor MFMA cluster
#pragma unroll
    for (int ks = 0; ks < 2; ++ks) {
#pragma unroll
      for (int c = 0; c < 4; ++c) {
        const int boff = (c * 16 + l16) * 64 + (((ks * 4 + quad) ^ xl) * 8);
        const s16x8 khv = *(const s16x8*)&KhS[pb][boff];
        const s16x8 klv = *(const s16x8*)&KlS[pb][boff];
        sacc[c] = __builtin_amdgcn_mfma_f32_16x16x32_bf16(khv, qh[ks], sacc[c], 0, 0, 0);
        sacc[c] = __builtin_amdgcn_mfma_f32_16x16x32_bf16(khv, ql[ks], sacc[c], 0, 0, 0);
        sacc[c] = __builtin_amdgcn_mfma_f32_16x16x32_bf16(klv, qh[ks], sacc[c], 0, 0, 0);
      }
    }
    __builtin_amdgcn_s_setprio(0);

    // ---- online softmax (per-lane row state), fused push + P store ----
    {
      float mx = sacc[0][0];
#pragma unroll
      for (int c = 0; c < 4; ++c)
#pragma unroll
        for (int r = 0; r < 4; ++r) mx = fmaxf(mx, sacc[c][r]);
      mx = fmaxf(mx, __shfl_xor(mx, 16));
      mx = fmaxf(mx, __shfl_xor(mx, 32));  // row max over all 64 keys of tile

      // defer-rescale: if no lane's max grew, alpha==1 exactly -> skip the pass
      if (__ballot(mx > m_r) != 0ull) {
        const float mn = fmaxf(m_r, mx);
        const float al = fexp2(m_r - mn);  // 0 on first tile
        m_r = mn;
#pragma unroll
        for (int c = 0; c < 4; ++c)
#pragma unroll
          for (int r = 0; r < 4; ++r) o_acc[c][r] *= al;
        l_r *= al;
      }

      // -15.88 < -11*log2(e): gate true whenever any pc can exceed pthr
      const bool anyhot = __ballot(mx - m_r > -15.88f) != 0ull;
      float rs = 0.0f;
#pragma unroll
      for (int c = 0; c < 4; ++c) {
        float pc[4];  // only 4 floats live at the pressure peak (reg diet)
#pragma unroll
        for (int r = 0; r < 4; ++r) {
          pc[r] = fexp2(sacc[c][r] - m_r);
          rs += pc[r];  // UNMASKED row sum (softmax normalizes before dropout)
        }
        if (anyhot) {
#pragma unroll
          for (int r = 0; r < 4; ++r) {
            const uint64_t mc = __ballot(pc[r] > pthr);
            if (mc != 0ull) {
              if (lbase + 64 <= CAP) {
                const int slot = lbase + (int)__popcll(mc & ((1ull << lane) - 1ull));
                if (pc[r] > pthr) {
                  Lm[w][slot] = ((uint32_t)l16 << 10) |
                                (uint32_t)(kbase + c * 16 + quad * 4 + r);
                  Lsv[w][slot] = sacc[c][r];  // raw logit (log2 domain)
                }
                lbase += (int)__popcll(mc);
              } else if (pc[r] > pthr) {  // overflow: inline exact dropout
                const uint32_t j =
                    (hbase + (uint32_t)(qbase + w * 16 + l16)) * (uint32_t)Sn +
                    (uint32_t)(kbase + c * 16 + quad * 4 + r);
                if (!keep_bit(j)) pc[r] = 0.0f;  // rs already added (unmasked)
              }
            }
          }
        }
        // P store: 4 consecutive keys -> b64, XOR-chunk swizzled (native cvt)
        s16x4 pk;
#pragma unroll
        for (int r = 0; r < 4; ++r) pk[r] = (short)f2bf_fast(pc[r]);
        const int pos = (c * 2 + (quad >> 1)) ^ xl;
        *(s16x4*)&PS[psw + l16 * 64 + pos * 8 + (quad & 1) * 4] = pk;
      }

      rs += __shfl_xor(rs, 16);
      rs += __shfl_xor(rs, 32);
      l_r += rs;
    }

    // ---- PV as O^T: A = Vt (LDS), B = P (LDS, same-wave RAW) ----
    __builtin_amdgcn_s_setprio(1);     // T5
#pragma unroll
    for (int ks2 = 0; ks2 < 2; ++ks2) {
      const s16x8 pfr = *(const s16x8*)&PS[psw + l16 * 64 + (((ks2 * 4 + quad) ^ xl) * 8)];
#pragma unroll
      for (int c = 0; c < 4; ++c) {
        const int voff = (c * 16 + l16) * 64 + (((ks2 * 4 + quad) ^ xl) * 8);
        const s16x8 vb = *(const s16x8*)&VtS[pb][voff];
        o_acc[c] = __builtin_amdgcn_mfma_f32_16x16x32_bf16(vb, pfr, o_acc[c], 0, 0, 0);
      }
    }
    __builtin_amdgcn_s_setprio(0);
  };

  // ---- ping-pong main loop: ONE barrier per tile, prefetch into other buffer ----
  for (int kt = 0; kt < NTILE; kt += 2) {
    __syncthreads();               // own vmcnt(0) drained -> buf0(kt) visible to all;
                                   // all waves done reading buf1 (tile kt-1)
    issue3(kt + 1, 1);             // kt+1 <= 15 always (NTILE even)
    tile_step(kt * TK, 0);
    __syncthreads();               // buf1(kt+1) visible; all done reading buf0(kt)
    if (kt + 2 < NTILE) issue3(kt + 2, 0);
    tile_step((kt + 1) * TK, 1);
  }

  // ---- drain: dense threefry over candidate list, subtract dropped p*V ----
  if (quad == 0) mfin[w][l16] = m_r;
  for (int e0 = 0; e0 < lbase; e0 += 64) {
    const int e = e0 + lane;
    const bool valid = e < lbase;
    const uint32_t meta = valid ? Lm[w][e] : 0u;
    const float sv = valid ? Lsv[w][e] : 0.0f;
    const uint32_t rwv = meta >> 10, keyv = meta & 1023u;
    const uint32_t grow = (uint32_t)(qbase + w * 16) + rwv;
    const uint32_t j = (hbase + grow) * (uint32_t)Sn + keyv;
    const int kb = keep_bit(j);  // dense: all 64 lanes productive
    uint64_t dm = __ballot(valid && !kb);
    while (dm != 0ull) {
      const int src = (int)__builtin_ctzll(dm);
      dm &= dm - 1ull;
      const uint32_t meta_s = (uint32_t)__builtin_amdgcn_readlane((int)meta, src);
      const float sv_s =
          __uint_as_float((uint32_t)__builtin_amdgcn_readlane((int)__float_as_uint(sv), src));
      const int rw = (int)(meta_s >> 10);
      const int key = (int)(meta_s & 1023u);
      const float p = fexp2(sv_s - mfin[w][rw]);   // log2 domain
      const float pb2 = bf2f(f2bf_fast(p));        // matches stored bf16(P) bits
      if (rw == l16) {  // the 4 quads owning column q participate
        const float* vp = V + ((size_t)bh * Sn + (size_t)key) * Dn;
#pragma unroll
        for (int c = 0; c < 4; ++c) {
          float4 vv = *(const float4*)(vp + c * 16 + quad * 4);
          o_acc[c][0] = fmaf(-pb2, bf2f(f2bf(vv.x)), o_acc[c][0]);
          o_acc[c][1] = fmaf(-pb2, bf2f(f2bf(vv.y)), o_acc[c][1]);
          o_acc[c][2] = fmaf(-pb2, bf2f(f2bf(vv.z)), o_acc[c][2]);
          o_acc[c][3] = fmaf(-pb2, bf2f(f2bf(vv.w)), o_acc[c][3]);
        }
      }
    }
  }

  // ---- epilogue: out[q][dv] = O^T / (l * 0.9); per-lane scalar scale ----
  {
    const float inv = 1.0f / (l_r * 0.9f);
    const size_t obase = ((size_t)bh * Sn + (size_t)(qbase + w * 16 + l16)) * Dn;
#pragma unroll
    for (int c = 0; c < 4; ++c) {
      float4 ov;
      ov.x = o_acc[c][0] * inv;
      ov.y = o_acc[c][1] * inv;
      ov.z = o_acc[c][2] * inv;
      ov.w = o_acc[c][3] * inv;
      *(float4*)(out + obase + c * 16 + quad * 4) = ov;
    }
  }
}

// ---------------- fallback (R3 kernel, verbatim): used only if ws too small ----------------
constexpr int KST = 72;
__global__ __launch_bounds__(NTF) void attn_fallback(
    const float* __restrict__ Q, const float* __restrict__ K,
    const float* __restrict__ V, const int* __restrict__ scale_ptr,
    float* __restrict__ out) {
  __shared__ uint16_t KhS[64 * KST];
  __shared__ uint16_t KlS[64 * KST];
  __shared__ uint16_t VtS[Dn * KST];
  __shared__ uint16_t PSf[4 * 16 * KST];

  const int t = threadIdx.x;
  const int w = t >> 6;
  const int lane = t & 63;
  const int l16 = lane & 15;
  const int quad = lane >> 4;
  const int b = blockIdx.z, h = blockIdx.y;
  const int qbase = blockIdx.x * 64;
  const size_t bh = (size_t)b * Hn + h;
  const float scale = (float)(*scale_ptr);
  const float* Kp = K + bh * Sn * Dn;
  const float* Vp = V + bh * Sn * Dn;

  const int qrow = qbase + w * 16 + l16;
  const float* Qp = Q + (bh * Sn + (size_t)qrow) * Dn;
  s16x8 qh[2], ql[2];
#pragma unroll
  for (int ks = 0; ks < 2; ++ks) {
    const float* src = Qp + ks * 32 + quad * 8;
    float4 x0 = *(const float4*)(src);
    float4 x1 = *(const float4*)(src + 4);
    float xv[8] = {x0.x, x0.y, x0.z, x0.w, x1.x, x1.y, x1.z, x1.w};
#pragma unroll
    for (int j = 0; j < 8; ++j) {
      uint16_t hb = f2bf(xv[j]);
      qh[ks][j] = (short)hb;
      ql[ks][j] = (short)f2bf(xv[j] - bf2f(hb));
    }
  }
  const int kr = t >> 2;
  const int qd = t & 3;
  float m_r[4], l_r[4];
#pragma unroll
  for (int r = 0; r < 4; ++r) { m_r[r] = -INFINITY; l_r[r] = 0.0f; }
  f32x4 o_acc[4];
#pragma unroll
  for (int c = 0; c < 4; ++c) o_acc[c] = (f32x4){0.f, 0.f, 0.f, 0.f};
  const uint32_t rowlin = ((uint32_t)(b * Hn + h)) * (uint32_t)Sn +
                          (uint32_t)(qbase + w * 16 + quad * 4);
  for (int kt = 0; kt < Sn / 64; ++kt) {
    const int kbase = kt * 64;
    __syncthreads();
    {
      const float* ksrc = Kp + (size_t)(kbase + kr) * Dn + qd * 16;
#pragma unroll
      for (int half = 0; half < 2; ++half) {
        float4 a = *(const float4*)(ksrc + half * 8);
        float4 b2 = *(const float4*)(ksrc + half * 8 + 4);
        float xs[8] = {a.x, a.y, a.z, a.w, b2.x, b2.y, b2.z, b2.w};
        s16x8 hv, lv;
#pragma unroll
        for (int j = 0; j < 8; ++j) {
          uint16_t hb = f2bf(xs[j]);
          hv[j] = (short)hb;
          lv[j] = (short)f2bf(xs[j] - bf2f(hb));
        }
        *(s16x8*)&KhS[kr * KST + qd * 16 + half * 8] = hv;
        *(s16x8*)&KlS[kr * KST + qd * 16 + half * 8] = lv;
      }
      const float* vsrc = Vp + (size_t)(kbase + kr) * Dn + qd * 16;
#pragma unroll
      for (int half = 0; half < 2; ++half) {
        float4 a = *(const float4*)(vsrc + half * 8);
        float4 b2 = *(const float4*)(vsrc + half * 8 + 4);
        float xs[8] = {a.x, a.y, a.z, a.w, b2.x, b2.y, b2.z, b2.w};
#pragma unroll
        for (int j = 0; j < 8; ++j)
          VtS[(qd * 16 + half * 8 + j) * KST + kr] = f2bf(xs[j]);
      }
    }
    __syncthreads();
    f32x4 sacc[4];
#pragma unroll
    for (int c = 0; c < 4; ++c) sacc[c] = (f32x4){0.f, 0.f, 0.f, 0.f};
#pragma unroll
    for (int ks = 0; ks < 2; ++ks) {
#pragma unroll
      for (int c = 0; c < 4; ++c) {
        const s16x8 bh_ = *(const s16x8*)&KhS[(c * 16 + l16) * KST + ks * 32 + quad * 8];
        const s16x8 bl_ = *(const s16x8*)&KlS[(c * 16 + l16) * KST + ks * 32 + quad * 8];
        sacc[c] = __builtin_amdgcn_mfma_f32_16x16x32_bf16(qh[ks], bh_, sacc[c], 0, 0, 0);
        sacc[c] = __builtin_amdgcn_mfma_f32_16x16x32_bf16(ql[ks], bh_, sacc[c], 0, 0, 0);
        sacc[c] = __builtin_amdgcn_mfma_f32_16x16x32_bf16(qh[ks], bl_, sacc[c], 0, 0, 0);
      }
    }
    float mx[4];
#pragma unroll
    for (int r = 0; r < 4; ++r) {
      mx[r] = sacc[0][r] * scale;
#pragma unroll
      for (int c = 1; c < 4; ++c) mx[r] = fmaxf(mx[r], sacc[c][r] * scale);
#pragma unroll
      for (int d = 1; d < 16; d <<= 1) mx[r] = fmaxf(mx[r], __shfl_xor(mx[r], d));
    }
    float al[4];
#pragma unroll
    for (int r = 0; r < 4; ++r) {
      const float mn = fmaxf(m_r[r], mx[r]);
      al[r] = __expf(m_r[r] - mn);
      m_r[r] = mn;
    }
#pragma unroll
    for (int c = 0; c < 4; ++c)
#pragma unroll
      for (int r = 0; r < 4; ++r) o_acc[c][r] *= al[r];
    float rs[4] = {0.f, 0.f, 0.f, 0.f};
#pragma unroll
    for (int c = 0; c < 4; ++c) {
#pragma unroll
      for (int r = 0; r < 4; ++r) {
        const float d = sacc[c][r] * scale - m_r[r];
        float pv = __expf(d);
        rs[r] += pv;
        if (d > -25.0f) {
          const uint32_t j = (rowlin + (uint32_t)r) * (uint32_t)Sn +
                             (uint32_t)(kbase + c * 16 + l16);
          if (!keep_bit(j)) pv = 0.0f;
        }
        PSf[(w * 16 + quad * 4 + r) * KST + c * 16 + l16] = f2bf(pv);
      }
    }
#pragma unroll
    for (int r = 0; r < 4; ++r) {
#pragma unroll
      for (int d = 1; d < 16; d <<= 1) rs[r] += __shfl_xor(rs[r], d);
      l_r[r] = l_r[r] * al[r] + rs[r];
    }
#pragma unroll
    for (int ks2 = 0; ks2 < 2; ++ks2) {
      const s16x8 pa = *(const s16x8*)&PSf[(w * 16 + l16) * KST + ks2 * 32 + quad * 8];
#pragma unroll
      for (int c = 0; c < 4; ++c) {
        const s16x8 vb = *(const s16x8*)&VtS[(c * 16 + l16) * KST + ks2 * 32 + quad * 8];
        o_acc[c] = __builtin_amdgcn_mfma_f32_16x16x32_bf16(pa, vb, o_acc[c], 0, 0, 0);
      }
    }
  }
  float inv[4];
#pragma unroll
  for (int r = 0; r < 4; ++r) inv[r] = 1.0f / (l_r[r] * 0.9f);
#pragma unroll
  for (int c = 0; c < 4; ++c)
#pragma unroll
    for (int r = 0; r < 4; ++r)
      out[(bh * Sn + (size_t)(qbase + w * 16 + quad * 4 + r)) * Dn + c * 16 + l16] =
          o_acc[c][r] * inv[r];
}

extern "C" void kernel_launch(void* const* d_in, const int* in_sizes, int n_in,
                              void* d_out, int out_size, void* d_ws, size_t ws_size,
                              hipStream_t stream) {
  const float* Q = (const float*)d_in[0];
  const float* K = (const float*)d_in[1];
  const float* V = (const float*)d_in[2];
  const int* sf = (const int*)d_in[3];
  float* out = (float*)d_out;

  constexpr size_t ARR = (size_t)Bn * Hn * Sn * Dn;  // 4,194,304 elems (8 MB bf16)
  const size_t need = 3 * ARR * sizeof(uint16_t);    // 24 MB

  if (ws_size >= need) {
    uint16_t* Khg = (uint16_t*)d_ws;
    uint16_t* Klg = Khg + ARR;
    uint16_t* Vtg = Klg + ARR;
    prep_kv<<<dim3(4, 64), NTF, 0, stream>>>(K, V, Khg, Klg, Vtg);
    attn_mfma7<<<dim3(Sn / TQM, Hn, Bn), NT, 0, stream>>>(Q, Khg, Klg, Vtg, V, sf, out);
  } else {
    attn_fallback<<<dim3(Sn / 64, Hn, Bn), NTF, 0, stream>>>(Q, K, V, sf, out);
  }
}

// Round 13
// 158.727 us; speedup vs baseline: 1.0300x; 1.0143x over previous
//
#include <hip/hip_runtime.h>
#include <hip/hip_bf16.h>
#include <stdint.h>
#include <math.h>

// Attention: out = dropout(softmax(8 * Q K^T)) V, B=4 H=16 S=1024 D=64 fp32.
// R22 = R21 + deferred l-reduction: rs cross-quad shuffles (2x shfl_xor) sat
// on the critical path between P-stores and PV every tile. al is row-uniform
// across quads (mx quad-reduced before m_r update), so each lane keeps a
// per-quad PARTIAL l_r (l_r = l_r*al + rs_partial); the full row reduction
// moves to ONE 2-shuffle pass in the epilogue. 30 of 32 shuffles removed,
// P-store->PV unblocked. Pure fp32 reassociation; no sync/layout change.
// Established this session: ~82us total-vs-attn gap is harness reset cost
// (invariant to prep coalescing R19 AND prep block-merge R21); occupancy
// escape geometrically blocked (grid 512 <-> dbuf LDS); deeper DMA pipe
// useless under __syncthreads drain (loads land within tile budget).
// attn side (proven): T1 XCD permutation (FETCH 110->22.5MB), T5 setprio,
// ping-pong dbuf ONE barrier/tile, NT=512 TQM=128, numerics diet (native
// cvts, log2-domain exp2, defer-rescale), S^T = K Q^T, deferred-correction
// dropout (threefry VERIFIED R2). prep: R21 merged coalesced version.

constexpr int Bn = 4, Hn = 16, Sn = 1024, Dn = 64;
constexpr int NT = 512;   // main kernel: 8 waves/block
constexpr int NTF = 256;  // prep + fallback block size
constexpr int TK = 64;
constexpr int TQM = 128;  // q rows per block (wave w owns rows w*16..w*16+15)
constexpr int CAP = 128;  // per-wave candidate list capacity (overflow path exact)
constexpr int NTILE = Sn / TK;  // 16

typedef short s16x8 __attribute__((ext_vector_type(8)));
typedef short s16x4 __attribute__((ext_vector_type(4)));
typedef float f32x4 __attribute__((ext_vector_type(4)));

__device__ __forceinline__ uint16_t f2bf(float x) {  // RNE float->bf16 (manual)
  uint32_t u = __float_as_uint(x);
  return (uint16_t)((u + 0x7fffu + ((u >> 16) & 1u)) >> 16);
}
__device__ __forceinline__ uint16_t f2bf_fast(float x) {  // RNE via v_cvt (fusable)
  return __builtin_bit_cast(uint16_t, __float2bfloat16(x));
}
__device__ __forceinline__ float bf2f(uint16_t h) {
  return __uint_as_float(((uint32_t)h) << 16);
}
__device__ __forceinline__ float fexp2(float x) {  // v_exp_f32 (2^x)
  return __builtin_amdgcn_exp2f(x);
}

__device__ __forceinline__ void tf_round(uint32_t& x0, uint32_t& x1, const int r) {
  x0 += x1;
  x1 = (x1 << r) | (x1 >> (32 - r));
  x1 ^= x0;
}

// threefry2x32, key(42)=(0,42), counter (0, j), bits = y0^y1  [VERIFIED R2]
__device__ __noinline__ int keep_bit(uint32_t j) {
  uint32_t x0 = 0u, x1 = j;
  const uint32_t k0 = 0u, k1v = 42u;
  const uint32_t k2v = k0 ^ k1v ^ 0x1BD11BDAu;
  x0 += k0; x1 += k1v;
  tf_round(x0, x1, 13); tf_round(x0, x1, 15); tf_round(x0, x1, 26); tf_round(x0, x1, 6);
  x0 += k1v; x1 += k2v + 1u;
  tf_round(x0, x1, 17); tf_round(x0, x1, 29); tf_round(x0, x1, 16); tf_round(x0, x1, 24);
  x0 += k2v; x1 += k0 + 2u;
  tf_round(x0, x1, 13); tf_round(x0, x1, 15); tf_round(x0, x1, 26); tf_round(x0, x1, 6);
  x0 += k0; x1 += k1v + 3u;
  tf_round(x0, x1, 17); tf_round(x0, x1, 29); tf_round(x0, x1, 16); tf_round(x0, x1, 24);
  x0 += k1v; x1 += k2v + 4u;
  tf_round(x0, x1, 13); tf_round(x0, x1, 15); tf_round(x0, x1, 26); tf_round(x0, x1, 6);
  x0 += k2v; x1 += k0 + 5u;
  uint32_t bits = x0 ^ x1;
  float u = __uint_as_float((bits >> 9) | 0x3f800000u) - 1.0f;
  return u < 0.9f;
}

// ---- pre-pass: K split + V transpose, swizzled bf16 tiles (R21 merged) ----
__global__ __launch_bounds__(NTF) void prep_kv(const float* __restrict__ K,
                                               const float* __restrict__ V,
                                               uint16_t* __restrict__ Khg,
                                               uint16_t* __restrict__ Klg,
                                               uint16_t* __restrict__ Vtg) {
  __shared__ float Vl[TK][Dn + 1];
  const int t = threadIdx.x;
  const int bh = blockIdx.y;   // 0..63
  for (int kt2 = 0; kt2 < 4; ++kt2) {
    const int kt = blockIdx.x * 4 + kt2;   // 0..15
    const size_t tile = ((size_t)bh * 16 + kt) * 4096;
    const size_t rowbase = (size_t)bh * Sn + (size_t)(kt * TK);

    if (kt2 != 0) __syncthreads();  // Vl reuse: prev transpose reads done
#pragma unroll
    for (int i = 0; i < 2; ++i) {
      const int r = i * 32 + (t >> 3);
      const int c0 = (t & 7) * 8;
      const float* ksrc = K + (rowbase + (size_t)r) * Dn + c0;
      float4 a = *(const float4*)(ksrc);
      float4 b = *(const float4*)(ksrc + 4);
      float xs[8] = {a.x, a.y, a.z, a.w, b.x, b.y, b.z, b.w};
      s16x8 hv, lv;
#pragma unroll
      for (int j = 0; j < 8; ++j) {
        uint16_t hb = f2bf_fast(xs[j]);
        hv[j] = (short)hb;
        lv[j] = (short)f2bf_fast(xs[j] - bf2f(hb));
      }
      const int sc = (t & 7) ^ (r & 7);   // chunk = c0/8 = t&7
      *(s16x8*)&Khg[tile + (size_t)r * 64 + sc * 8] = hv;
      *(s16x8*)&Klg[tile + (size_t)r * 64 + sc * 8] = lv;
      const float* vsrc = V + (rowbase + (size_t)r) * Dn + c0;
      float4 va = *(const float4*)(vsrc);
      float4 vb = *(const float4*)(vsrc + 4);
      *(float4*)&Vl[r][c0] = va;
      *(float4*)&Vl[r][c0 + 4] = vb;
    }
    __syncthreads();
    {
      const int r = t >> 2, qd = t & 3;
#pragma unroll
      for (int half = 0; half < 2; ++half) {
        s16x8 ov;
#pragma unroll
        for (int j = 0; j < 8; ++j)
          ov[j] = (short)f2bf_fast(Vl[qd * 16 + half * 8 + j][r]);
        const int sc = (qd * 2 + half) ^ (r & 7);
        *(s16x8*)&Vtg[tile + (size_t)r * 64 + sc * 8] = ov;
      }
    }
  }
}

// -------- main flash kernel: S^T orientation, TQ=128, 8 waves, dbuf ping-pong --------
__global__ __launch_bounds__(NT, 4) void attn_mfma7(
    const float* __restrict__ Q, const uint16_t* __restrict__ Khg,
    const uint16_t* __restrict__ Klg, const uint16_t* __restrict__ Vtg,
    const float* __restrict__ V, const int* __restrict__ scale_ptr,
    float* __restrict__ out) {
  __shared__ uint16_t KhS[2][TK * Dn];   // 2 x 8 KB ping-pong (DMA dest, swizzled)
  __shared__ uint16_t KlS[2][TK * Dn];
  __shared__ uint16_t VtS[2][TK * Dn];
  __shared__ uint16_t PS[8 * 16 * 64];   // per-wave P[q][key], XOR-chunk swizzled
  __shared__ uint32_t Lm[8][CAP];        // per-wave candidate list: (rw<<10)|key
  __shared__ float Lsv[8][CAP];          // candidate raw logit s (log2 domain)
  __shared__ float mfin[8][16];          // per-wave final row max (log2 domain)

  const int t = threadIdx.x;
  const int w = t >> 6;                  // 0..7
  const int lane = t & 63;
  const int l16 = lane & 15;
  const int quad = lane >> 4;
  const int xl = l16 & 7;                // XOR swizzle key

  // ---- T1: XCD-aware work permutation. Grid (8,16,4); XCD = linear%8 = x.
  // bh = x*8+(y&7), qb = (y>>3)*4+z [bijective]: all 8 q-blocks of one bh on
  // one XCD -> per-XCD ws footprint 3MB fits its 4MB L2 (FETCH 110->22.5MB).
  const int bh = blockIdx.x * 8 + (blockIdx.y & 7);
  const int qb = ((blockIdx.y >> 3) << 2) | blockIdx.z;
  const int qbase = qb * TQM;
  // log2(e) folded into the Q pre-scale: all logits live in the log2 domain.
  const float qscale = (float)(*scale_ptr) * 1.44269504089f;
  const float pthr = 1.670170079e-5f;    // exp(-11), in the p domain (unchanged)

  // per-wave DMA segment: wave w covers elements [w*512, w*512+512) of each tile
  const int eoff = w * 512 + lane * 8;
  const size_t tbase = (size_t)bh * 16 * 4096;
  const int psw = w * 1024;              // per-wave PS base (elements)

  auto issue3 = [&](int ti, int pb) {    // stage Kh,Kl,Vt of tile ti into buf pb
    const size_t tile = tbase + (size_t)ti * 4096;
    __builtin_amdgcn_global_load_lds(
        (const __attribute__((address_space(1))) uint32_t*)(Khg + tile + eoff),
        (__attribute__((address_space(3))) uint32_t*)(&KhS[pb][eoff]), 16, 0, 0);
    __builtin_amdgcn_global_load_lds(
        (const __attribute__((address_space(1))) uint32_t*)(Klg + tile + eoff),
        (__attribute__((address_space(3))) uint32_t*)(&KlS[pb][eoff]), 16, 0, 0);
    __builtin_amdgcn_global_load_lds(
        (const __attribute__((address_space(1))) uint32_t*)(Vtg + tile + eoff),
        (__attribute__((address_space(3))) uint32_t*)(&VtS[pb][eoff]), 16, 0, 0);
  };

  // prologue: tile 0 -> buf0 in flight; Q load/split overlaps it
  issue3(0, 0);

  // ---- Q B-frags (pre-scaled, log2 domain): wave w owns q rows qbase+w*16+l16 ----
  s16x8 qh[2], ql[2];
  {
    const int qrow = qbase + w * 16 + l16;
    const float* src = Q + ((size_t)bh * Sn + (size_t)qrow) * Dn;
#pragma unroll
    for (int ks = 0; ks < 2; ++ks) {
      float4 x0 = *(const float4*)(src + ks * 32 + quad * 8);
      float4 x1 = *(const float4*)(src + ks * 32 + quad * 8 + 4);
      float xv[8] = {x0.x, x0.y, x0.z, x0.w, x1.x, x1.y, x1.z, x1.w};
#pragma unroll
      for (int j = 0; j < 8; ++j) {
        const float xs = xv[j] * qscale;
        uint16_t hb = f2bf_fast(xs);
        qh[ks][j] = (short)hb;
        ql[ks][j] = (short)f2bf_fast(xs - bf2f(hb));
      }
    }
  }

  // per-lane softmax state: ONE q per lane (log2 domain).
  // R22: l_r is a per-QUAD PARTIAL sum (this lane's 16 keys/tile); al is
  // row-uniform across quads, so partials scale consistently; full row
  // reduction deferred to the epilogue (one 2-shuffle pass).
  float m_r = -INFINITY, l_r = 0.0f;
  // O^T accumulator: o_acc[c][r] = O[q = l16][dv = c*16+quad*4+r]
  f32x4 o_acc[4];
#pragma unroll
  for (int c = 0; c < 4; ++c) o_acc[c] = (f32x4){0.f, 0.f, 0.f, 0.f};

  const uint32_t hbase = (uint32_t)bh * (uint32_t)Sn;
  int lbase = 0;  // per-wave list fill (wave-uniform)

  // one tile's QK -> softmax -> PV, reading buffers [pb]
  auto tile_step = [&](int kbase, int pb) {
    // ---- S^T = K Q^T: A = K tile (LDS), B = Q (regs), split-bf16 3-MFMA ----
    f32x4 sacc[4];
#pragma unroll
    for (int c = 0; c < 4; ++c) sacc[c] = (f32x4){0.f, 0.f, 0.f, 0.f};
    __builtin_amdgcn_s_setprio(1);     // T5: favor MFMA cluster
#pragma unroll
    for (int ks = 0; ks < 2; ++ks) {
#pragma unroll
      for (int c = 0; c < 4; ++c) {
        const int boff = (c * 16 + l16) * 64 + (((ks * 4 + quad) ^ xl) * 8);
        const s16x8 khv = *(const s16x8*)&KhS[pb][boff];
        const s16x8 klv = *(const s16x8*)&KlS[pb][boff];
        sacc[c] = __builtin_amdgcn_mfma_f32_16x16x32_bf16(khv, qh[ks], sacc[c], 0, 0, 0);
        sacc[c] = __builtin_amdgcn_mfma_f32_16x16x32_bf16(khv, ql[ks], sacc[c], 0, 0, 0);
        sacc[c] = __builtin_amdgcn_mfma_f32_16x16x32_bf16(klv, qh[ks], sacc[c], 0, 0, 0);
      }
    }
    __builtin_amdgcn_s_setprio(0);

    // ---- online softmax (per-lane row state), fused push + P store ----
    {
      float mx = sacc[0][0];
#pragma unroll
      for (int c = 0; c < 4; ++c)
#pragma unroll
        for (int r = 0; r < 4; ++r) mx = fmaxf(mx, sacc[c][r]);
      mx = fmaxf(mx, __shfl_xor(mx, 16));
      mx = fmaxf(mx, __shfl_xor(mx, 32));  // row max over all 64 keys of tile

      // defer-rescale: if no lane's max grew, alpha==1 exactly -> skip the pass
      if (__ballot(mx > m_r) != 0ull) {
        const float mn = fmaxf(m_r, mx);
        const float al = fexp2(m_r - mn);  // 0 on first tile
        m_r = mn;
#pragma unroll
        for (int c = 0; c < 4; ++c)
#pragma unroll
          for (int r = 0; r < 4; ++r) o_acc[c][r] *= al;
        l_r *= al;                         // partial scales consistently (al row-uniform)
      }

      // -15.88 < -11*log2(e): gate true whenever any pc can exceed pthr
      const bool anyhot = __ballot(mx - m_r > -15.88f) != 0ull;
      float rs = 0.0f;
#pragma unroll
      for (int c = 0; c < 4; ++c) {
        float pc[4];  // only 4 floats live at the pressure peak (reg diet)
#pragma unroll
        for (int r = 0; r < 4; ++r) {
          pc[r] = fexp2(sacc[c][r] - m_r);
          rs += pc[r];  // UNMASKED partial row sum (this quad's 16 keys)
        }
        if (anyhot) {
#pragma unroll
          for (int r = 0; r < 4; ++r) {
            const uint64_t mc = __ballot(pc[r] > pthr);
            if (mc != 0ull) {
              if (lbase + 64 <= CAP) {
                const int slot = lbase + (int)__popcll(mc & ((1ull << lane) - 1ull));
                if (pc[r] > pthr) {
                  Lm[w][slot] = ((uint32_t)l16 << 10) |
                                (uint32_t)(kbase + c * 16 + quad * 4 + r);
                  Lsv[w][slot] = sacc[c][r];  // raw logit (log2 domain)
                }
                lbase += (int)__popcll(mc);
              } else if (pc[r] > pthr) {  // overflow: inline exact dropout
                const uint32_t j =
                    (hbase + (uint32_t)(qbase + w * 16 + l16)) * (uint32_t)Sn +
                    (uint32_t)(kbase + c * 16 + quad * 4 + r);
                if (!keep_bit(j)) pc[r] = 0.0f;  // rs already added (unmasked)
              }
            }
          }
        }
        // P store: 4 consecutive keys -> b64, XOR-chunk swizzled (native cvt)
        s16x4 pk;
#pragma unroll
        for (int r = 0; r < 4; ++r) pk[r] = (short)f2bf_fast(pc[r]);
        const int pos = (c * 2 + (quad >> 1)) ^ xl;
        *(s16x4*)&PS[psw + l16 * 64 + pos * 8 + (quad & 1) * 4] = pk;
      }

      l_r += rs;   // R22: NO cross-quad shuffles here — deferred to epilogue
    }

    // ---- PV as O^T: A = Vt (LDS), B = P (LDS, same-wave RAW) ----
    __builtin_amdgcn_s_setprio(1);     // T5
#pragma unroll
    for (int ks2 = 0; ks2 < 2; ++ks2) {
      const s16x8 pfr = *(const s16x8*)&PS[psw + l16 * 64 + (((ks2 * 4 + quad) ^ xl) * 8)];
#pragma unroll
      for (int c = 0; c < 4; ++c) {
        const int voff = (c * 16 + l16) * 64 + (((ks2 * 4 + quad) ^ xl) * 8);
        const s16x8 vb = *(const s16x8*)&VtS[pb][voff];
        o_acc[c] = __builtin_amdgcn_mfma_f32_16x16x32_bf16(vb, pfr, o_acc[c], 0, 0, 0);
      }
    }
    __builtin_amdgcn_s_setprio(0);
  };

  // ---- ping-pong main loop: ONE barrier per tile, prefetch into other buffer ----
  for (int kt = 0; kt < NTILE; kt += 2) {
    __syncthreads();               // own vmcnt(0) drained -> buf0(kt) visible to all;
                                   // all waves done reading buf1 (tile kt-1)
    issue3(kt + 1, 1);             // kt+1 <= 15 always (NTILE even)
    tile_step(kt * TK, 0);
    __syncthreads();               // buf1(kt+1) visible; all done reading buf0(kt)
    if (kt + 2 < NTILE) issue3(kt + 2, 0);
    tile_step((kt + 1) * TK, 1);
  }

  // ---- drain: dense threefry over candidate list, subtract dropped p*V ----
  if (quad == 0) mfin[w][l16] = m_r;
  for (int e0 = 0; e0 < lbase; e0 += 64) {
    const int e = e0 + lane;
    const bool valid = e < lbase;
    const uint32_t meta = valid ? Lm[w][e] : 0u;
    const float sv = valid ? Lsv[w][e] : 0.0f;
    const uint32_t rwv = meta >> 10, keyv = meta & 1023u;
    const uint32_t grow = (uint32_t)(qbase + w * 16) + rwv;
    const uint32_t j = (hbase + grow) * (uint32_t)Sn + keyv;
    const int kb = keep_bit(j);  // dense: all 64 lanes productive
    uint64_t dm = __ballot(valid && !kb);
    while (dm != 0ull) {
      const int src = (int)__builtin_ctzll(dm);
      dm &= dm - 1ull;
      const uint32_t meta_s = (uint32_t)__builtin_amdgcn_readlane((int)meta, src);
      const float sv_s =
          __uint_as_float((uint32_t)__builtin_amdgcn_readlane((int)__float_as_uint(sv), src));
      const int rw = (int)(meta_s >> 10);
      const int key = (int)(meta_s & 1023u);
      const float p = fexp2(sv_s - mfin[w][rw]);   // log2 domain
      const float pb2 = bf2f(f2bf_fast(p));        // matches stored bf16(P) bits
      if (rw == l16) {  // the 4 quads owning column q participate
        const float* vp = V + ((size_t)bh * Sn + (size_t)key) * Dn;
#pragma unroll
        for (int c = 0; c < 4; ++c) {
          float4 vv = *(const float4*)(vp + c * 16 + quad * 4);
          o_acc[c][0] = fmaf(-pb2, bf2f(f2bf(vv.x)), o_acc[c][0]);
          o_acc[c][1] = fmaf(-pb2, bf2f(f2bf(vv.y)), o_acc[c][1]);
          o_acc[c][2] = fmaf(-pb2, bf2f(f2bf(vv.z)), o_acc[c][2]);
          o_acc[c][3] = fmaf(-pb2, bf2f(f2bf(vv.w)), o_acc[c][3]);
        }
      }
    }
  }

  // ---- epilogue: deferred l reduction (R22), then out = O^T / (l * 0.9) ----
  {
    l_r += __shfl_xor(l_r, 16);
    l_r += __shfl_xor(l_r, 32);        // full row sum, all quads agree
    const float inv = 1.0f / (l_r * 0.9f);
    const size_t obase = ((size_t)bh * Sn + (size_t)(qbase + w * 16 + l16)) * Dn;
#pragma unroll
    for (int c = 0; c < 4; ++c) {
      float4 ov;
      ov.x = o_acc[c][0] * inv;
      ov.y = o_acc[c][1] * inv;
      ov.z = o_acc[c][2] * inv;
      ov.w = o_acc[c][3] * inv;
      *(float4*)(out + obase + c * 16 + quad * 4) = ov;
    }
  }
}

// ---------------- fallback (R3 kernel, verbatim): used only if ws too small ----------------
constexpr int KST = 72;
__global__ __launch_bounds__(NTF) void attn_fallback(
    const float* __restrict__ Q, const float* __restrict__ K,
    const float* __restrict__ V, const int* __restrict__ scale_ptr,
    float* __restrict__ out) {
  __shared__ uint16_t KhS[64 * KST];
  __shared__ uint16_t KlS[64 * KST];
  __shared__ uint16_t VtS[Dn * KST];
  __shared__ uint16_t PSf[4 * 16 * KST];

  const int t = threadIdx.x;
  const int w = t >> 6;
  const int lane = t & 63;
  const int l16 = lane & 15;
  const int quad = lane >> 4;
  const int b = blockIdx.z, h = blockIdx.y;
  const int qbase = blockIdx.x * 64;
  const size_t bh = (size_t)b * Hn + h;
  const float scale = (float)(*scale_ptr);
  const float* Kp = K + bh * Sn * Dn;
  const float* Vp = V + bh * Sn * Dn;

  const int qrow = qbase + w * 16 + l16;
  const float* Qp = Q + (bh * Sn + (size_t)qrow) * Dn;
  s16x8 qh[2], ql[2];
#pragma unroll
  for (int ks = 0; ks < 2; ++ks) {
    const float* src = Qp + ks * 32 + quad * 8;
    float4 x0 = *(const float4*)(src);
    float4 x1 = *(const float4*)(src + 4);
    float xv[8] = {x0.x, x0.y, x0.z, x0.w, x1.x, x1.y, x1.z, x1.w};
#pragma unroll
    for (int j = 0; j < 8; ++j) {
      uint16_t hb = f2bf(xv[j]);
      qh[ks][j] = (short)hb;
      ql[ks][j] = (short)f2bf(xv[j] - bf2f(hb));
    }
  }
  const int kr = t >> 2;
  const int qd = t & 3;
  float m_r[4], l_r[4];
#pragma unroll
  for (int r = 0; r < 4; ++r) { m_r[r] = -INFINITY; l_r[r] = 0.0f; }
  f32x4 o_acc[4];
#pragma unroll
  for (int c = 0; c < 4; ++c) o_acc[c] = (f32x4){0.f, 0.f, 0.f, 0.f};
  const uint32_t rowlin = ((uint32_t)(b * Hn + h)) * (uint32_t)Sn +
                          (uint32_t)(qbase + w * 16 + quad * 4);
  for (int kt = 0; kt < Sn / 64; ++kt) {
    const int kbase = kt * 64;
    __syncthreads();
    {
      const float* ksrc = Kp + (size_t)(kbase + kr) * Dn + qd * 16;
#pragma unroll
      for (int half = 0; half < 2; ++half) {
        float4 a = *(const float4*)(ksrc + half * 8);
        float4 b2 = *(const float4*)(ksrc + half * 8 + 4);
        float xs[8] = {a.x, a.y, a.z, a.w, b2.x, b2.y, b2.z, b2.w};
        s16x8 hv, lv;
#pragma unroll
        for (int j = 0; j < 8; ++j) {
          uint16_t hb = f2bf(xs[j]);
          hv[j] = (short)hb;
          lv[j] = (short)f2bf(xs[j] - bf2f(hb));
        }
        *(s16x8*)&KhS[kr * KST + qd * 16 + half * 8] = hv;
        *(s16x8*)&KlS[kr * KST + qd * 16 + half * 8] = lv;
      }
      const float* vsrc = Vp + (size_t)(kbase + kr) * Dn + qd * 16;
#pragma unroll
      for (int half = 0; half < 2; ++half) {
        float4 a = *(const float4*)(vsrc + half * 8);
        float4 b2 = *(const float4*)(vsrc + half * 8 + 4);
        float xs[8] = {a.x, a.y, a.z, a.w, b2.x, b2.y, b2.z, b2.w};
#pragma unroll
        for (int j = 0; j < 8; ++j)
          VtS[(qd * 16 + half * 8 + j) * KST + kr] = f2bf(xs[j]);
      }
    }
    __syncthreads();
    f32x4 sacc[4];
#pragma unroll
    for (int c = 0; c < 4; ++c) sacc[c] = (f32x4){0.f, 0.f, 0.f, 0.f};
#pragma unroll
    for (int ks = 0; ks < 2; ++ks) {
#pragma unroll
      for (int c = 0; c < 4; ++c) {
        const s16x8 bh_ = *(const s16x8*)&KhS[(c * 16 + l16) * KST + ks * 32 + quad * 8];
        const s16x8 bl_ = *(const s16x8*)&KlS[(c * 16 + l16) * KST + ks * 32 + quad * 8];
        sacc[c] = __builtin_amdgcn_mfma_f32_16x16x32_bf16(qh[ks], bh_, sacc[c], 0, 0, 0);
        sacc[c] = __builtin_amdgcn_mfma_f32_16x16x32_bf16(ql[ks], bh_, sacc[c], 0, 0, 0);
        sacc[c] = __builtin_amdgcn_mfma_f32_16x16x32_bf16(qh[ks], bl_, sacc[c], 0, 0, 0);
      }
    }
    float mx[4];
#pragma unroll
    for (int r = 0; r < 4; ++r) {
      mx[r] = sacc[0][r] * scale;
#pragma unroll
      for (int c = 1; c < 4; ++c) mx[r] = fmaxf(mx[r], sacc[c][r] * scale);
#pragma unroll
      for (int d = 1; d < 16; d <<= 1) mx[r] = fmaxf(mx[r], __shfl_xor(mx[r], d));
    }
    float al[4];
#pragma unroll
    for (int r = 0; r < 4; ++r) {
      const float mn = fmaxf(m_r[r], mx[r]);
      al[r] = __expf(m_r[r] - mn);
      m_r[r] = mn;
    }
#pragma unroll
    for (int c = 0; c < 4; ++c)
#pragma unroll
      for (int r = 0; r < 4; ++r) o_acc[c][r] *= al[r];
    float rs[4] = {0.f, 0.f, 0.f, 0.f};
#pragma unroll
    for (int c = 0; c < 4; ++c) {
#pragma unroll
      for (int r = 0; r < 4; ++r) {
        const float d = sacc[c][r] * scale - m_r[r];
        float pv = __expf(d);
        rs[r] += pv;
        if (d > -25.0f) {
          const uint32_t j = (rowlin + (uint32_t)r) * (uint32_t)Sn +
                             (uint32_t)(kbase + c * 16 + l16);
          if (!keep_bit(j)) pv = 0.0f;
        }
        PSf[(w * 16 + quad * 4 + r) * KST + c * 16 + l16] = f2bf(pv);
      }
    }
#pragma unroll
    for (int r = 0; r < 4; ++r) {
#pragma unroll
      for (int d = 1; d < 16; d <<= 1) rs[r] += __shfl_xor(rs[r], d);
      l_r[r] = l_r[r] * al[r] + rs[r];
    }
#pragma unroll
    for (int ks2 = 0; ks2 < 2; ++ks2) {
      const s16x8 pa = *(const s16x8*)&PSf[(w * 16 + l16) * KST + ks2 * 32 + quad * 8];
#pragma unroll
      for (int c = 0; c < 4; ++c) {
        const s16x8 vb = *(const s16x8*)&VtS[(c * 16 + l16) * KST + ks2 * 32 + quad * 8];
        o_acc[c] = __builtin_amdgcn_mfma_f32_16x16x32_bf16(pa, vb, o_acc[c], 0, 0, 0);
      }
    }
  }
  float inv[4];
#pragma unroll
  for (int r = 0; r < 4; ++r) inv[r] = 1.0f / (l_r[r] * 0.9f);
#pragma unroll
  for (int c = 0; c < 4; ++c)
#pragma unroll
    for (int r = 0; r < 4; ++r)
      out[(bh * Sn + (size_t)(qbase + w * 16 + quad * 4 + r)) * Dn + c * 16 + l16] =
          o_acc[c][r] * inv[r];
}

extern "C" void kernel_launch(void* const* d_in, const int* in_sizes, int n_in,
                              void* d_out, int out_size, void* d_ws, size_t ws_size,
                              hipStream_t stream) {
  const float* Q = (const float*)d_in[0];
  const float* K = (const float*)d_in[1];
  const float* V = (const float*)d_in[2];
  const int* sf = (const int*)d_in[3];
  float* out = (float*)d_out;

  constexpr size_t ARR = (size_t)Bn * Hn * Sn * Dn;  // 4,194,304 elems (8 MB bf16)
  const size_t need = 3 * ARR * sizeof(uint16_t);    // 24 MB

  if (ws_size >= need) {
    uint16_t* Khg = (uint16_t*)d_ws;
    uint16_t* Klg = Khg + ARR;
    uint16_t* Vtg = Klg + ARR;
    prep_kv<<<dim3(4, 64), NTF, 0, stream>>>(K, V, Khg, Klg, Vtg);
    attn_mfma7<<<dim3(Sn / TQM, Hn, Bn), NT, 0, stream>>>(Q, Khg, Klg, Vtg, V, sf, out);
  } else {
    attn_fallback<<<dim3(Sn / 64, Hn, Bn), NTF, 0, stream>>>(Q, K, V, sf, out);
  }
}